// Round 2
// baseline (662.717 us; speedup 1.0000x reference)
//
#include <hip/hip_runtime.h>

// Correlation layer, restructured for LDS-issue efficiency:
// each thread: 4 pixels along w (float4) x 27 displacements (3 i-rows x 9 j).
// threadIdx.z = i-group (0..2) -> each wave is one i-group (wave-uniform).
// Per channel per thread: 10 ds_read_b128 vs 108 FMAs -> VALU-bound.

#define B_  8
#define C_  128
#define H_  128
#define W_  192
#define HW_ (H_*W_)
#define HALO 4
#define WT  32              // tile width (px)
#define HT  8               // tile height (px)
#define CC  8               // channels staged per chunk
#define X2R (HT + 2*HALO)   // 16 rows
#define X2C (WT + 2*HALO)   // 40 cols (160 B stride, 16B-aligned rows)
#define X1C 36              // x1 row stride pad (144 B, 16B-aligned, breaks stride-32)

__global__ __launch_bounds__(192, 2) void corr_kernel(
    const float* __restrict__ x1, const float* __restrict__ x2,
    float* __restrict__ out)
{
    __shared__ float x2s[CC][X2R][X2C];   // 20480 B
    __shared__ float x1s[CC][HT][X1C];    //  9216 B

    const int tx = threadIdx.x;          // 0..7 : 4-px column group
    const int ty = threadIdx.y;          // 0..7 : row within tile
    const int g  = threadIdx.z;          // 0..2 : i-group
    const int tid = tx + 8*ty + 64*g;    // 0..191

    const int w0t = blockIdx.x * WT;
    const int h0t = blockIdx.y * HT;
    const int b   = blockIdx.z;

    const float* x1b = x1 + (size_t)b * C_ * HW_;
    const float* x2b = x2 + (size_t)b * C_ * HW_;

    float acc[27][4];
    #pragma unroll
    for (int k = 0; k < 27; k++) {
        acc[k][0] = 0.f; acc[k][1] = 0.f; acc[k][2] = 0.f; acc[k][3] = 0.f;
    }

    for (int c0 = 0; c0 < C_; c0 += CC) {
        __syncthreads();   // previous chunk's reads done before overwrite

        // stage x2 halo tile (zero-fill OOB)
        for (int e = tid; e < CC * X2R * X2C; e += 192) {
            const int cc  = e / (X2R * X2C);
            const int rem = e - cc * (X2R * X2C);
            const int r   = rem / X2C;
            const int col = rem - r * X2C;
            const int gh = h0t - HALO + r;
            const int gw = w0t - HALO + col;
            float v = 0.f;
            if ((unsigned)gh < (unsigned)H_ && (unsigned)gw < (unsigned)W_)
                v = x2b[(size_t)(c0 + cc) * HW_ + gh * W_ + gw];
            x2s[cc][r][col] = v;
        }
        // stage x1 tile (vectorized float4, fully in-bounds)
        for (int e = tid; e < CC * HT * (WT/4); e += 192) {
            const int cc  = e / (HT * (WT/4));
            const int rem = e - cc * (HT * (WT/4));
            const int r   = rem / (WT/4);
            const int c4  = rem - r * (WT/4);
            const float4 v = *(const float4*)(x1b + (size_t)(c0 + cc) * HW_
                                              + (h0t + r) * W_ + w0t + c4*4);
            *(float4*)&x1s[cc][r][c4*4] = v;
        }
        __syncthreads();

        #pragma unroll
        for (int cc = 0; cc < CC; cc++) {
            const float4 a = *(const float4*)&x1s[cc][ty][tx*4];
            const float av[4] = {a.x, a.y, a.z, a.w};
            #pragma unroll
            for (int il = 0; il < 3; il++) {
                // global row = (h0t+ty) + (g*3 + il - 4); tile row = ty + 3g + il
                const float* row = &x2s[cc][ty + 3*g + il][tx*4];
                const float4 r0 = *(const float4*)(row);
                const float4 r1 = *(const float4*)(row + 4);
                const float4 r2 = *(const float4*)(row + 8);
                const float rr[12] = {r0.x, r0.y, r0.z, r0.w,
                                      r1.x, r1.y, r1.z, r1.w,
                                      r2.x, r2.y, r2.z, r2.w};
                #pragma unroll
                for (int j = 0; j < 9; j++) {
                    #pragma unroll
                    for (int p = 0; p < 4; p++) {
                        acc[il*9 + j][p] = fmaf(av[p], rr[j + p], acc[il*9 + j][p]);
                    }
                }
            }
        }
    }

    // epilogue: scale + write 27 (or 26) float4 channels
    const float scale = 0.08838834764831845f;   // 1/sqrt(128)
    const int h  = h0t + ty;
    const int w0 = w0t + tx*4;
    float* outb = out + (size_t)b * 80 * HW_ + (size_t)h * W_ + w0;
    #pragma unroll
    for (int il = 0; il < 3; il++) {
        #pragma unroll
        for (int j = 0; j < 9; j++) {
            const int gi = (3*g + il) * 9 + j;   // 0..80, wave-uniform
            if (gi == 40) continue;              // skip (0,0) displacement
            const int ch = gi - (gi > 40 ? 1 : 0);
            float4 v;
            v.x = acc[il*9 + j][0] * scale;
            v.y = acc[il*9 + j][1] * scale;
            v.z = acc[il*9 + j][2] * scale;
            v.w = acc[il*9 + j][3] * scale;
            *(float4*)(outb + (size_t)ch * HW_) = v;
        }
    }
}

extern "C" void kernel_launch(void* const* d_in, const int* in_sizes, int n_in,
                              void* d_out, int out_size, void* d_ws, size_t ws_size,
                              hipStream_t stream) {
    const float* x1 = (const float*)d_in[0];
    const float* x2 = (const float*)d_in[1];
    float* out = (float*)d_out;

    dim3 block(8, 8, 3);                       // 192 threads = 3 waves
    dim3 grid(W_ / WT, H_ / HT, B_);           // 6 x 16 x 8 = 768 blocks
    corr_kernel<<<grid, block, 0, stream>>>(x1, x2, out);
}

// Round 3
// 506.096 us; speedup vs baseline: 1.3095x; 1.3095x over previous
//
#include <hip/hip_runtime.h>

// Correlation layer v3: small accumulator tile so it provably stays in VGPRs.
// Thread = 4 px (float4 along w) x 1 displacement row x 9 j  -> 36 accs.
// threadIdx.z = displacement row i (0..8), one wave per i (wave-uniform).
// Per channel per thread: 4 ds_read_b128 + 36 v_fmac_f32.

#define B_  8
#define C_  128
#define H_  128
#define W_  192
#define HW_ (H_*W_)
#define HALO 4
#define WT  32              // tile width (px)
#define HT  8               // tile height (px)
#define CC  8               // channels staged per chunk
#define X2R (HT + 2*HALO)   // 16
#define X2C (WT + 2*HALO)   // 40
#define X2SZ (X2R*X2C)      // 640 floats per channel
#define NTHREADS 576        // 8 x 8 x 9

__global__ __launch_bounds__(NTHREADS) void corr_kernel(
    const float* __restrict__ x1, const float* __restrict__ x2,
    float* __restrict__ out)
{
    __shared__ float x2s[CC][X2R][X2C];   // 8*640*4  = 20480 B
    __shared__ float x1s[CC][HT][WT];     // 8*256*4  =  8192 B

    const int tx = threadIdx.x;           // 0..7 : 4-px column group
    const int ty = threadIdx.y;           // 0..7 : row within tile
    const int iz = threadIdx.z;           // 0..8 : displacement row
    const int tid = tx + 8*ty + 64*iz;    // 0..575

    const int w0t = blockIdx.x * WT;
    const int h0t = blockIdx.y * HT;
    const int b   = blockIdx.z;

    const float* x1b = x1 + (size_t)b * C_ * HW_;
    const float* x2b = x2 + (size_t)b * C_ * HW_;

    float acc[9][4];
    #pragma unroll
    for (int j = 0; j < 9; j++)
        #pragma unroll
        for (int p = 0; p < 4; p++) acc[j][p] = 0.f;

    for (int c0 = 0; c0 < C_; c0 += CC) {
        __syncthreads();   // previous chunk's reads done before overwrite

        // stage x2 halo tile (zero-fill OOB): CC*640 scalar elems
        for (int e = tid; e < CC * X2SZ; e += NTHREADS) {
            const int cc  = e / X2SZ;
            const int rem = e - cc * X2SZ;
            const int r   = rem / X2C;
            const int col = rem - r * X2C;
            const int gh = h0t - HALO + r;
            const int gw = w0t - HALO + col;
            float v = 0.f;
            if ((unsigned)gh < (unsigned)H_ && (unsigned)gw < (unsigned)W_)
                v = x2b[(size_t)(c0 + cc) * HW_ + gh * W_ + gw];
            (&x2s[0][0][0])[e] = v;
        }
        // stage x1 tile: CC*8*8 float4 elems (512 <= 576 threads, 1 iter)
        if (tid < CC * HT * (WT/4)) {
            const int e   = tid;
            const int cc  = e >> 6;            // /64
            const int rem = e & 63;
            const int r   = rem >> 3;          // /8
            const int c4  = rem & 7;
            const float4 v = *(const float4*)(x1b + (size_t)(c0 + cc) * HW_
                                              + (h0t + r) * W_ + w0t + c4*4);
            *(float4*)&x1s[cc][r][c4*4] = v;
        }
        __syncthreads();

        #pragma unroll 2
        for (int cc = 0; cc < CC; cc++) {
            const float4 a = *(const float4*)&x1s[cc][ty][tx*4];
            const float av[4] = {a.x, a.y, a.z, a.w};
            const float* row = &x2s[cc][ty + iz][tx*4];
            const float4 r0 = *(const float4*)(row);
            const float4 r1 = *(const float4*)(row + 4);
            const float4 r2 = *(const float4*)(row + 8);
            const float rr[12] = {r0.x, r0.y, r0.z, r0.w,
                                  r1.x, r1.y, r1.z, r1.w,
                                  r2.x, r2.y, r2.z, r2.w};
            #pragma unroll
            for (int j = 0; j < 9; j++)
                #pragma unroll
                for (int p = 0; p < 4; p++)
                    acc[j][p] = fmaf(av[p], rr[j + p], acc[j][p]);
        }
    }

    // epilogue: scale + write up to 9 float4 channels
    const float scale = 0.08838834764831845f;   // 1/sqrt(128)
    const int h  = h0t + ty;
    const int w0 = w0t + tx*4;
    float* outb = out + (size_t)b * 80 * HW_ + (size_t)h * W_ + w0;
    #pragma unroll
    for (int j = 0; j < 9; j++) {
        const int gi = iz * 9 + j;          // 0..80, wave-uniform
        if (gi == 40) continue;             // skip (0,0) displacement
        const int ch = gi - (gi > 40 ? 1 : 0);
        float4 v;
        v.x = acc[j][0] * scale;
        v.y = acc[j][1] * scale;
        v.z = acc[j][2] * scale;
        v.w = acc[j][3] * scale;
        *(float4*)(outb + (size_t)ch * HW_) = v;
    }
}

extern "C" void kernel_launch(void* const* d_in, const int* in_sizes, int n_in,
                              void* d_out, int out_size, void* d_ws, size_t ws_size,
                              hipStream_t stream) {
    const float* x1 = (const float*)d_in[0];
    const float* x2 = (const float*)d_in[1];
    float* out = (float*)d_out;

    dim3 block(8, 8, 9);                       // 576 threads = 9 waves
    dim3 grid(W_ / WT, H_ / HT, B_);           // 6 x 16 x 8 = 768 blocks
    corr_kernel<<<grid, block, 0, stream>>>(x1, x2, out);
}

// Round 4
// 451.374 us; speedup vs baseline: 1.4682x; 1.1212x over previous
//
#include <hip/hip_runtime.h>

// Correlation layer v4.
// Thread = 4 px (float4 along w) x 1 displacement row (iz) x 9 j -> 36 accs.
// Fixes vs v3 (365us): __launch_bounds__(576,2) lifts the default 64-VGPR cap
// (R1/R3 showed compiler targets 8 waves/SIMD -> AGPR-shuffles the acc tile);
// x1 served from global (L1-resident, 1KiB/ch/block) instead of LDS; x2
// staging indices hoisted out of the chunk loop (was ~80 VALU/thread/chunk).

#define B_  8
#define C_  128
#define H_  128
#define W_  192
#define HW_ (H_*W_)
#define HALO 4
#define WT  32              // tile width (px)
#define HT  8               // tile height (px)
#define CC  8               // channels staged per chunk
#define X2R (HT + 2*HALO)   // 16
#define X2C (WT + 2*HALO)   // 40
#define X2SZ (X2R*X2C)      // 640 floats per channel
#define NTHREADS 576        // 8 x 8 x 9

__global__ __launch_bounds__(NTHREADS, 2) void corr_kernel(
    const float* __restrict__ x1, const float* __restrict__ x2,
    float* __restrict__ out)
{
    __shared__ float x2s[CC][X2SZ];   // 8*640*4 = 20480 B

    const int tx = threadIdx.x;           // 0..7 : 4-px column group
    const int ty = threadIdx.y;           // 0..7 : row within tile
    const int iz = threadIdx.z;           // 0..8 : displacement row
    const int tid = tx + 8*ty + 64*iz;    // 0..575

    const int w0t = blockIdx.x * WT;
    const int h0t = blockIdx.y * HT;
    const int b   = blockIdx.z;

    const float* x1b = x1 + (size_t)b * C_ * HW_;
    const float* x2b = x2 + (size_t)b * C_ * HW_;

    // ---- staging indices, computed ONCE ----
    // element 0: e0 = tid (all threads), element 1: e1 = tid+576 (tid<64 only)
    const int e0 = tid;
    const int r0s = e0 / X2C, c0s = e0 - r0s * X2C;
    const int gh0 = h0t - HALO + r0s, gw0 = w0t - HALO + c0s;
    const bool inb0 = ((unsigned)gh0 < (unsigned)H_) & ((unsigned)gw0 < (unsigned)W_);
    const int g0 = gh0 * W_ + gw0;

    const int e1 = tid + NTHREADS;
    const bool has1 = (e1 < X2SZ);
    const int r1s = e1 / X2C, c1s = e1 - r1s * X2C;
    const int gh1 = h0t - HALO + r1s, gw1 = w0t - HALO + c1s;
    const bool inb1 = has1 & ((unsigned)gh1 < (unsigned)H_) & ((unsigned)gw1 < (unsigned)W_);
    const int g1 = gh1 * W_ + gw1;

    // x1: this thread's 4 pixels, loaded straight from global (L1-resident)
    const float* x1t = x1b + (h0t + ty) * W_ + w0t + 4 * tx;
    // x2 window base in LDS (per channel offset added in loop)
    const int woff = (ty + iz) * X2C + 4 * tx;

    float acc[9][4];
    #pragma unroll
    for (int j = 0; j < 9; j++)
        #pragma unroll
        for (int p = 0; p < 4; p++) acc[j][p] = 0.f;

    for (int c0 = 0; c0 < C_; c0 += CC) {
        __syncthreads();   // previous chunk's reads done before overwrite

        // stage x2 halo tile (zero-fill OOB), precomputed indices
        #pragma unroll
        for (int cc = 0; cc < CC; cc++) {
            const float* p = x2b + (size_t)(c0 + cc) * HW_;
            x2s[cc][e0] = inb0 ? p[g0] : 0.f;
            if (has1) x2s[cc][e1] = inb1 ? p[g1] : 0.f;
        }
        __syncthreads();

        #pragma unroll 2
        for (int cc = 0; cc < CC; cc++) {
            const float4 a = *(const float4*)(x1t + (size_t)(c0 + cc) * HW_);
            const float av[4] = {a.x, a.y, a.z, a.w};
            const float* row = &x2s[cc][woff];
            const float4 w0 = *(const float4*)(row);
            const float4 w1 = *(const float4*)(row + 4);
            const float4 w2 = *(const float4*)(row + 8);
            const float rr[12] = {w0.x, w0.y, w0.z, w0.w,
                                  w1.x, w1.y, w1.z, w1.w,
                                  w2.x, w2.y, w2.z, w2.w};
            #pragma unroll
            for (int j = 0; j < 9; j++)
                #pragma unroll
                for (int p = 0; p < 4; p++)
                    acc[j][p] = fmaf(av[p], rr[j + p], acc[j][p]);
        }
    }

    // epilogue: scale + write up to 9 float4 channels
    const float scale = 0.08838834764831845f;   // 1/sqrt(128)
    const int h  = h0t + ty;
    const int w0 = w0t + tx*4;
    float* outb = out + (size_t)b * 80 * HW_ + (size_t)h * W_ + w0;
    #pragma unroll
    for (int j = 0; j < 9; j++) {
        const int gi = iz * 9 + j;          // 0..80, wave-uniform
        if (gi == 40) continue;             // skip (0,0) displacement
        const int ch = gi - (gi > 40 ? 1 : 0);
        float4 v;
        v.x = acc[j][0] * scale;
        v.y = acc[j][1] * scale;
        v.z = acc[j][2] * scale;
        v.w = acc[j][3] * scale;
        *(float4*)(outb + (size_t)ch * HW_) = v;
    }
}

extern "C" void kernel_launch(void* const* d_in, const int* in_sizes, int n_in,
                              void* d_out, int out_size, void* d_ws, size_t ws_size,
                              hipStream_t stream) {
    const float* x1 = (const float*)d_in[0];
    const float* x2 = (const float*)d_in[1];
    float* out = (float*)d_out;

    dim3 block(8, 8, 9);                       // 576 threads = 9 waves
    dim3 grid(W_ / WT, H_ / HT, B_);           // 6 x 16 x 8 = 768 blocks
    corr_kernel<<<grid, block, 0, stream>>>(x1, x2, out);
}